// Round 6
// baseline (6582.254 us; speedup 1.0000x reference)
//
#include <hip/hip_runtime.h>
#include <hip/hip_cooperative_groups.h>
#include <cstdint>
#include <cstddef>

namespace cg = cooperative_groups;

typedef _Float16 f16;
typedef _Float16 h8v  __attribute__((ext_vector_type(8)));
typedef float    f32x4 __attribute__((ext_vector_type(4)));

static constexpr int BATCH  = 128;
static constexpr int TSTEPS = 512;
static constexpr int NT     = 256;

// worker blocks per layer (NJ = hidden units per block: 8,4,8,8)
static constexpr int TB1 = 80, TB2 = 100, TB3 = 32, TB4 = 32;
static constexpr int TNB   = TB1 + TB2 + TB3 + TB4;   // 244
static constexpr int NGRID = TNB;                     // direct polling: no control blocks

// ---------------- workspace layout (byte offsets) ----------------
// all h tensors batch-major: [slot][b][j]  (f16)
template<int RING> struct WS {
  static constexpr size_t XT  = 0;                                   // f16 [512][128][64]
  static constexpr size_t H1  = XT + 512ull * 128 * 64 * 2;          // f16 [RING][128][640]
  static constexpr size_t H2  = H1 + (size_t)RING * 128 * 640 * 2 + 64;
  static constexpr size_t H3  = H2 + (size_t)RING * 128 * 400 * 2 + 64;
  static constexpr size_t H4  = H3 + (size_t)RING * 128 * 256 * 2 + 64;
  static constexpr size_t PK1 = H4 + (size_t)RING * 128 * 256 * 2 + 64; // f16 [TB][4NJ][KPAD]
  static constexpr size_t PK2 = PK1 + (size_t)TB1 * 32 * 704  * 2;
  static constexpr size_t PK3 = PK2 + (size_t)TB2 * 16 * 1056 * 2;
  static constexpr size_t PK4 = PK3 + (size_t)TB3 * 32 * 672  * 2;
  static constexpr size_t BAR = PK4 + (size_t)TB4 * 32 * 512  * 2;   // 8 KB: U[244] flags
  static constexpr size_t ZERO= BAR + 8192;                          // zeroed h[-1] region
  static constexpr size_t END = ZERO + 163840;                       // 128*640+slack f16
};
// U[bid] = number of steps block bid has completed (monotonic, distinct slot per block)

struct KParams {
  const float *x;
  const float *k1, *r1, *b1, *k2, *r2, *b2, *k3, *r3, *b3, *k4, *r4, *b4;
  const float *wd1, *bd1, *wd2, *bd2, *wd3, *bd3, *wd4, *bd4, *wd5, *bd5, *wd6, *bd6;
  float *out;
  char *ws;
};

__device__ __forceinline__ float sigm(float v) { return 1.f / (1.f + expf(-v)); }

// ---- agent-scope (cross-XCD coherent) primitives: flags + h publish ----
__device__ __forceinline__ uint64_t c_load8(const void* p) {
  return __hip_atomic_load((const uint64_t*)p, __ATOMIC_RELAXED, __HIP_MEMORY_SCOPE_AGENT);
}
__device__ __forceinline__ void c_store2(void* p, unsigned short v) {
  __hip_atomic_store((unsigned short*)p, v, __ATOMIC_RELAXED, __HIP_MEMORY_SCOPE_AGENT);
}
__device__ __forceinline__ unsigned short c_load2(const void* p) {
  return __hip_atomic_load((const unsigned short*)p, __ATOMIC_RELAXED, __HIP_MEMORY_SCOPE_AGENT);
}
__device__ __forceinline__ unsigned u_load(const unsigned* p) {
  return __hip_atomic_load(p, __ATOMIC_RELAXED, __HIP_MEMORY_SCOPE_AGENT);
}
__device__ __forceinline__ void u_store(unsigned* p, unsigned v) {
  __hip_atomic_store(p, v, __ATOMIC_RELAXED, __HIP_MEMORY_SCOPE_AGENT);
}
__device__ __forceinline__ void acq_fence() {
  __builtin_amdgcn_fence(__ATOMIC_ACQUIRE, "agent");
}

// ---------------- weight prepack: pack[blk][n][k], n = gate*NJ + jj, f16, zero-padded K ----------------
__device__ void prepack_layer(const float* __restrict__ gk, const float* __restrict__ gr,
                              f16* __restrict__ pack, int DIN, int H, int NJ, int KPAD,
                              int TB, int gtid, int gstr) {
  const int KREAL = DIN + H;
  const int NGC = 4 * NJ;
  const long total = (long)TB * NGC * KPAD;
  for (long e = gtid; e < total; e += gstr) {
    const int  k   = (int)(e % KPAD);
    const long r   = e / KPAD;
    const int  n   = (int)(r % NGC);
    const int  blk = (int)(r / NGC);
    const int  g   = n / NJ, jj = n % NJ;
    const int  j   = blk * NJ + jj;
    float v = 0.f;
    if (k < DIN)        v = gk[(size_t)k * 4 * H + (size_t)g * H + j];
    else if (k < KREAL) v = gr[(size_t)(k - DIN) * 4 * H + (size_t)g * H + j];
    pack[e] = (f16)v;
  }
}

// ---------------- MFMA LSTM layer role ----------------
// FETCH(buf, chunk): A-fragment loads for one chunk of C ksteps.
// Big path (RING==TSTEPS): PLAIN cached uint4 loads — h-ring addresses are
// write-once per run, so cold-miss L2 fills are coherent (validated r3) and
// redundant same-XCD reads become L2 hits. Fallback path: sc1 8B loads.
#define FETCH(PP, CC) do { \
  _Pragma("unroll") \
  for (int ii_ = 0; ii_ < C; ++ii_) { \
    const int ks_ = (CC) * C + ii_; \
    if (ks_ < KS) { \
      const int k_ = ks_ * 32 + kg; \
      _Pragma("unroll") \
      for (int m_ = 0; m_ < 2; ++m_) { \
        const int bmv_ = m_ ? bm1 : bm0; \
        uint4 v_ = make_uint4(0u, 0u, 0u, 0u); \
        if constexpr (SEQM) { \
          if (k_ < DIN)        v_ = *(const uint4*)(inP + (size_t)bmv_ * DIN + k_); \
          else if (k_ < KREAL) v_ = *(const uint4*)(inH + (size_t)bmv_ * H + (k_ - DIN)); \
        } else { \
          if (k_ < DIN) { \
            const f16* p_ = inP + (size_t)bmv_ * DIN + k_; \
            if constexpr (SEQIN) { \
              ((uint64_t*)&v_)[0] = *(const uint64_t*)p_; \
              ((uint64_t*)&v_)[1] = *(const uint64_t*)(p_ + 4); \
            } else { \
              ((uint64_t*)&v_)[0] = c_load8(p_); \
              ((uint64_t*)&v_)[1] = c_load8(p_ + 4); \
            } \
          } else if (k_ < KREAL) { \
            const f16* p_ = inH + (size_t)bmv_ * H + (k_ - DIN); \
            ((uint64_t*)&v_)[0] = c_load8(p_); \
            ((uint64_t*)&v_)[1] = c_load8(p_ + 4); \
          } \
        } \
        ab[PP][ii_][m_] = v_; \
      } \
    } \
  } \
} while (0)

// COMPUTE(buf, chunk): B-fragments from LDS + MFMAs for one chunk
#define COMPUTE(PP, CC) do { \
  _Pragma("unroll") \
  for (int ii_ = 0; ii_ < C; ++ii_) { \
    const int ks_ = (CC) * C + ii_; \
    if (ks_ < KS) { \
      const int kb_ = ks_ * 32; \
      h8v bf_[NTI]; \
      _Pragma("unroll") \
      for (int nt_ = 0; nt_ < NTI; ++nt_) \
        bf_[nt_] = *(const h8v*)(wlds + (size_t)(nt_ * 16 + l15) * WROW + kb_ + kg); \
      _Pragma("unroll") \
      for (int m_ = 0; m_ < 2; ++m_) { \
        union { uint4 u; h8v v; } af_; \
        af_.u = ab[PP][ii_][m_]; \
        _Pragma("unroll") \
        for (int nt_ = 0; nt_ < NTI; ++nt_) \
          acc[m_][nt_] = __builtin_amdgcn_mfma_f32_16x16x32_f16(af_.v, bf_[nt_], acc[m_][nt_], 0, 0, 0); \
      } \
    } \
  } \
} while (0)

template<int DIN, int H, int NJ, int LIDX, bool SEQIN, int RING>
__device__ void lstm_role(int blk, int bid, const f16* lo_base, f16* ownH,
                          const f16* pack, const float* __restrict__ gbias,
                          const f16* zreg, char* smem, unsigned* U,
                          int pf, int pc, int of, int oc, int nf, int nc) {
  constexpr bool SEQM = (RING == TSTEPS);
  constexpr int KREAL = DIN + H;
  constexpr int KS    = (KREAL + 31) / 32;
  constexpr int KPAD  = KS * 32;
  constexpr int NGC   = 4 * NJ;
  constexpr int NTI   = NGC / 16;          // N-tiles (1 or 2)
  constexpr int WROW  = KPAD + 8;          // weight LDS row (f16)
  constexpr int ZROW  = 132;               // z LDS row (f32)
  constexpr int C     = 6;                 // ksteps per chunk
  constexpr int NC    = (KS + C - 1) / C;
  static_assert(NC <= 6, "NC");
  static_assert(NGC % 16 == 0 && (DIN % 8) == 0 && (KREAL % 8) == 0, "geom");

  const int tid  = threadIdx.x;
  const int w    = tid >> 6, lane = tid & 63;
  const int l15  = lane & 15;
  const int kg   = (lane >> 4) * 8;
  const int bm0  = w * 32 + l15;
  const int bm1  = bm0 + 16;

  f16*   wlds = (f16*)smem;
  float* z    = (float*)(smem + (size_t)NGC * WROW * 2);

  // ---- load this block's weights to LDS once ----
  {
    const f16* src = pack + (size_t)blk * NGC * KPAD;
    constexpr int RU = KPAD / 8;
    for (int u = tid; u < NGC * RU; u += NT) {
      const int n = u / RU, k8 = u % RU;
      *(uint4*)(wlds + (size_t)n * WROW + k8 * 8) =
          *(const uint4*)(src + (size_t)n * KPAD + k8 * 8);
    }
  }
  __syncthreads();

  // ---- epilogue ownership: thread -> (jj, 4 consecutive batches) ----
  const int jj = tid >> 5, bg = tid & 31, b0e = bg * 4;
  const bool epi = (tid < NJ * 32);
  const int j = blk * NJ + (epi ? jj : 0);
  const float4 bias = make_float4(gbias[j], gbias[H + j], gbias[2 * H + j], gbias[3 * H + j]);
  float cst[4] = {0.f, 0.f, 0.f, 0.f};

  // ---- direct-poll assignment: thread tid watches one peer/prev/next flag ----
  const int ncc = SEQM ? 0 : nc;
  int kind = 0;                       // 0 none, 1 prev(>=t+1), 2 own(>=t), 3 next(>=t-(RING-1))
  const unsigned* myU = nullptr;
  if (tid < pc)                 { kind = 1; myU = &U[pf + tid]; }
  else if (tid < pc + oc)       { kind = 2; myU = &U[of + tid - pc]; }
  else if (tid < pc + oc + ncc) { kind = 3; myU = &U[nf + tid - pc - oc]; }

  for (int t = 0; t < TSTEPS; ++t) {
    // ---- dataflow wait: single-hop, parallel per-thread flag polling ----
    {
      const int need = (kind == 1) ? (t + 1) : (kind == 2 ? t : t - (RING - 1));
      int cond = kind ? ((int)u_load(myU) >= need) : 1;
      while (!__syncthreads_and(cond)) {
        if (!cond) {
          cond = ((int)u_load(myU) >= need);        // monotonic: stays true once true
          if (!cond) __builtin_amdgcn_s_sleep(2);   // light throttle on miss only
        }
      }
    }

    const f16* inP = SEQIN ? lo_base + (size_t)t * DIN * BATCH
                           : lo_base + (size_t)(t & (RING - 1)) * DIN * BATCH;
    const f16* inH = (t == 0) ? zreg
                              : ownH + (size_t)((t - 1) & (RING - 1)) * H * BATCH;

    f32x4 acc[2][NTI];
    {
      const f32x4 zz = {0.f, 0.f, 0.f, 0.f};
      #pragma unroll
      for (int m_ = 0; m_ < 2; ++m_)
        #pragma unroll
        for (int nt_ = 0; nt_ < NTI; ++nt_) acc[m_][nt_] = zz;
    }

    uint4 ab[3][C][2];

    // ---- software-pipelined K loop: 3-deep chunk prefetch, no barriers ----
    FETCH(0, 0);
    if constexpr (NC > 1) FETCH(1, 1);
    if constexpr (NC > 2) FETCH(2, 2);
    COMPUTE(0, 0);
    if constexpr (NC > 1) { if constexpr (NC > 3) FETCH(0, 3); COMPUTE(1, 1); }
    if constexpr (NC > 2) { if constexpr (NC > 4) FETCH(1, 4); COMPUTE(2, 2); }
    if constexpr (NC > 3) { if constexpr (NC > 5) FETCH(2, 5); COMPUTE(0, 3); }
    if constexpr (NC > 4) COMPUTE(1, 4);
    if constexpr (NC > 5) COMPUTE(2, 5);

    // ---- D fragments -> z[gatecol][batch] in LDS ----
    #pragma unroll
    for (int m_ = 0; m_ < 2; ++m_)
      #pragma unroll
      for (int nt_ = 0; nt_ < NTI; ++nt_)
        *(f32x4*)(z + (size_t)(nt_ * 16 + l15) * ZROW + w * 32 + m_ * 16 + (lane >> 4) * 4) =
            acc[m_][nt_];
    __syncthreads();

    // ---- epilogue: gates, state, batch-major f16 h store (sc1 publish) ----
    if (epi) {
      const float* zb = z + b0e;
      const f32x4 zi = *(const f32x4*)(zb + (size_t)(0 * NJ + jj) * ZROW);
      const f32x4 zf = *(const f32x4*)(zb + (size_t)(1 * NJ + jj) * ZROW);
      const f32x4 zg = *(const f32x4*)(zb + (size_t)(2 * NJ + jj) * ZROW);
      const f32x4 zo = *(const f32x4*)(zb + (size_t)(3 * NJ + jj) * ZROW);
      f16* dst = ownH + (size_t)(t & (RING - 1)) * H * BATCH + j;
      #pragma unroll
      for (int q = 0; q < 4; ++q) {
        const float ig = sigm(zi[q] + bias.x);
        const float fg = sigm(zf[q] + bias.y);
        const float gg = tanhf(zg[q] + bias.z);
        const float og = sigm(zo[q] + bias.w);
        cst[q] = fg * cst[q] + ig * gg;
        const float hv = og * tanhf(cst[q]);
        union { f16 h; unsigned short u; } o2; o2.h = (f16)hv;
        c_store2(dst + (size_t)(b0e + q) * H, o2.u);
      }
    }
    asm volatile("s_waitcnt vmcnt(0)" ::: "memory");   // per-wave h-store drain
    __syncthreads();                                    // all waves drained
    if (tid == 0) u_store(&U[bid], (unsigned)(t + 1));  // distinct-slot single-hop publish
  }
}
#undef FETCH
#undef COMPUTE

// ---------------- dense head ----------------
__device__ void dense_stage(const float* in, float* outb,
                            const float* __restrict__ w, const float* __restrict__ bias,
                            int din, int dout, bool relu) {
  for (int jc = threadIdx.x; jc < dout; jc += NT) {
    float s = bias[jc];
    for (int d = 0; d < din; ++d) s += in[d] * w[(size_t)d * dout + jc];
    outb[jc] = relu ? fmaxf(s, 0.f) : s;
  }
  __syncthreads();
}

constexpr size_t cmax(size_t a, size_t b) { return a > b ? a : b; }
constexpr size_t wlz(int NGC, int KPAD) {
  return (size_t)NGC * (KPAD + 8) * 2 + (size_t)NGC * 132 * 4;
}
static constexpr size_t SMEM_BYTES =
    cmax(cmax(wlz(32, 704), wlz(16, 1056)),
         cmax(cmax(wlz(32, 672), wlz(32, 512)), (size_t)4096));
static_assert(SMEM_BYTES <= 65536, "LDS");

// ---------------- fused cooperative kernel ----------------
template<int RING>
__global__ __launch_bounds__(NT, 1) void fused_kernel(KParams p) {
  using L = WS<RING>;
  cg::grid_group grid = cg::this_grid();
  __shared__ __attribute__((aligned(16))) char smem[SMEM_BYTES];

  char* ws = p.ws;
  unsigned* U = (unsigned*)(ws + L::BAR);          // U[244] per-block step flags
  const f16* zreg = (const f16*)(ws + L::ZERO);
  const int tid  = threadIdx.x;
  const int bid  = blockIdx.x;
  const int gtid = bid * NT + tid;
  const int gstr = NGRID * NT;

  // ---- phase 0a: prepack weights (f16, [blk][gatecol][k], K zero-padded to x32) ----
  prepack_layer(p.k1, p.r1, (f16*)(ws + L::PK1), 64,  640, 8, 704,  TB1, gtid, gstr);
  prepack_layer(p.k2, p.r2, (f16*)(ws + L::PK2), 640, 400, 4, 1056, TB2, gtid, gstr);
  prepack_layer(p.k3, p.r3, (f16*)(ws + L::PK3), 400, 256, 8, 672,  TB3, gtid, gstr);
  prepack_layer(p.k4, p.r4, (f16*)(ws + L::PK4), 256, 256, 8, 512,  TB4, gtid, gstr);

  // ---- phase 0b: x [128][512][64] f32 -> xT [512][128][64] f16 (batch-major) ----
  {
    f16* xT = (f16*)(ws + L::XT);
    const long total = (long)TSTEPS * BATCH * 8;
    for (long u = gtid; u < total; u += gstr) {
      const int  d8 = (int)(u & 7);
      const long r  = u >> 3;
      const int  b  = (int)(r & (BATCH - 1));
      const int  t  = (int)(r >> 7);
      const float* src = p.x + ((size_t)b * TSTEPS + t) * 64 + d8 * 8;
      const float4 v0 = *(const float4*)src;
      const float4 v1 = *(const float4*)(src + 4);
      h8v o;
      o[0] = (f16)v0.x; o[1] = (f16)v0.y; o[2] = (f16)v0.z; o[3] = (f16)v0.w;
      o[4] = (f16)v1.x; o[5] = (f16)v1.y; o[6] = (f16)v1.z; o[7] = (f16)v1.w;
      *(h8v*)(xT + ((size_t)t * BATCH + b) * 64 + d8 * 8) = o;
    }
  }

  grid.sync();   // publish packs/xT device-wide
  acq_fence();   // once per run: drop any stale ring lines from a prior launch

  // ---- phase 1: dataflow-pipelined 4-layer LSTM scan (MFMA, direct polling) ----
  constexpr int O2 = TB1, O3 = TB1 + TB2, O4 = TB1 + TB2 + TB3;
  if (bid < O2) {
    lstm_role< 64, 640, 8, 0, true , RING>(bid, bid, (const f16*)(ws + L::XT),
        (f16*)(ws + L::H1), (const f16*)(ws + L::PK1), p.b1, zreg, smem, U,
        0, 0, 0, TB1, O2, TB2);
  } else if (bid < O3) {
    lstm_role<640, 400, 4, 1, false, RING>(bid - O2, bid, (const f16*)(ws + L::H1),
        (f16*)(ws + L::H2), (const f16*)(ws + L::PK2), p.b2, zreg, smem, U,
        0, TB1, O2, TB2, O3, TB3);
  } else if (bid < O4) {
    lstm_role<400, 256, 8, 2, false, RING>(bid - O3, bid, (const f16*)(ws + L::H2),
        (f16*)(ws + L::H3), (const f16*)(ws + L::PK3), p.b3, zreg, smem, U,
        O2, TB2, O3, TB3, O4, TB4);
  } else {
    lstm_role<256, 256, 8, 3, false, RING>(bid - O4, bid, (const f16*)(ws + L::H3),
        (f16*)(ws + L::H4), (const f16*)(ws + L::PK4), p.b4, zreg, smem, U,
        O3, TB3, O4, TB4, 0, 0);
  }

  // ---- phase 2: dense head ----
  if (bid < BATCH) {
    {
      int cond = (tid < TB4) ? ((int)u_load(&U[O4 + tid]) >= TSTEPS) : 1;
      while (!__syncthreads_and(cond)) {
        if (!cond) {
          cond = ((int)u_load(&U[O4 + tid]) >= TSTEPS);
          if (!cond) __builtin_amdgcn_s_sleep(2);
        }
      }
    }
    const int b = bid;
    float* A = (float*)smem;
    float* B = (float*)smem + 512;
    const f16* h4 = (const f16*)(ws + L::H4)
                  + (size_t)((TSTEPS - 1) & (RING - 1)) * 256 * BATCH + (size_t)b * 256;
    for (int d = tid; d < 256; d += NT) {
      union { unsigned short u; f16 h; } cc;
      cc.u = c_load2(h4 + d);
      A[d] = (float)cc.h;
    }
    __syncthreads();
    dense_stage(A, B, p.wd1, p.bd1, 256, 512, true);
    dense_stage(B, A, p.wd2, p.bd2, 512, 256, true);
    dense_stage(A, B, p.wd3, p.bd3, 256, 128, true);
    dense_stage(B, A, p.wd4, p.bd4, 128, 64,  true);
    dense_stage(A, B, p.wd5, p.bd5, 64,  16,  true);
    dense_stage(B, A, p.wd6, p.bd6, 16,  3,   false);
    if (tid == 0) {
      float z0 = A[0], z1 = A[1], z2 = A[2];
      float m  = fmaxf(fmaxf(z0, z1), z2);
      float e0 = expf(z0 - m), e1 = expf(z1 - m), e2 = expf(z2 - m);
      float s  = e0 + e1 + e2;
      p.out[b * 3 + 0] = e0 / s;
      p.out[b * 3 + 1] = e1 / s;
      p.out[b * 3 + 2] = e2 / s;
    }
  }
}

// ---------------- launch ----------------
extern "C" void kernel_launch(void* const* d_in, const int* in_sizes, int n_in,
                              void* d_out, int out_size, void* d_ws, size_t ws_size,
                              hipStream_t stream) {
  (void)in_sizes; (void)n_in; (void)out_size;
  KParams prm;
  prm.x  = (const float*)d_in[0];
  prm.k1 = (const float*)d_in[1];  prm.r1 = (const float*)d_in[2];  prm.b1 = (const float*)d_in[3];
  prm.k2 = (const float*)d_in[4];  prm.r2 = (const float*)d_in[5];  prm.b2 = (const float*)d_in[6];
  prm.k3 = (const float*)d_in[7];  prm.r3 = (const float*)d_in[8];  prm.b3 = (const float*)d_in[9];
  prm.k4 = (const float*)d_in[10]; prm.r4 = (const float*)d_in[11]; prm.b4 = (const float*)d_in[12];
  prm.wd1 = (const float*)d_in[13]; prm.bd1 = (const float*)d_in[14];
  prm.wd2 = (const float*)d_in[15]; prm.bd2 = (const float*)d_in[16];
  prm.wd3 = (const float*)d_in[17]; prm.bd3 = (const float*)d_in[18];
  prm.wd4 = (const float*)d_in[19]; prm.bd4 = (const float*)d_in[20];
  prm.wd5 = (const float*)d_in[21]; prm.bd5 = (const float*)d_in[22];
  prm.wd6 = (const float*)d_in[23]; prm.bd6 = (const float*)d_in[24];
  prm.out = (float*)d_out;
  prm.ws  = (char*)d_ws;

  const bool big = ws_size >= WS<TSTEPS>::END;
  const size_t bar_off = big ? WS<TSTEPS>::BAR : WS<4>::BAR;
  // zero the flag area AND the h[-1] zero-region (contiguous)
  hipMemsetAsync((char*)d_ws + bar_off, 0, 8192 + 163840, stream);

  void* args[] = { &prm };
  if (big) {
    hipLaunchCooperativeKernel((void*)fused_kernel<TSTEPS>, dim3(NGRID), dim3(NT),
                               args, 0, stream);
  } else {
    hipLaunchCooperativeKernel((void*)fused_kernel<4>, dim3(NGRID), dim3(NT),
                               args, 0, stream);
  }
}

// Round 7
// 5003.086 us; speedup vs baseline: 1.3156x; 1.3156x over previous
//
#include <hip/hip_runtime.h>
#include <hip/hip_cooperative_groups.h>
#include <cstdint>
#include <cstddef>

namespace cg = cooperative_groups;

typedef _Float16 f16;
typedef _Float16 h8v  __attribute__((ext_vector_type(8)));
typedef float    f32x4 __attribute__((ext_vector_type(4)));

static constexpr int BATCH  = 128;
static constexpr int TSTEPS = 512;
static constexpr int NT     = 256;

// worker blocks per layer (NJ = hidden units per block: 8,4,8,8)
static constexpr int TB1 = 80, TB2 = 100, TB3 = 32, TB4 = 32;
static constexpr int TNB   = TB1 + TB2 + TB3 + TB4;   // 244
static constexpr int NGRID = TNB + 4;                 // + 4 control blocks

// ---------------- workspace layout (byte offsets) ----------------
// all h tensors batch-major: [slot][b][j]  (f16)
template<int RING> struct WS {
  static constexpr size_t XT  = 0;                                   // f16 [512][128][64]
  static constexpr size_t H1  = XT + 512ull * 128 * 64 * 2;          // f16 [RING][128][640]
  static constexpr size_t H2  = H1 + (size_t)RING * 128 * 640 * 2 + 64;
  static constexpr size_t H3  = H2 + (size_t)RING * 128 * 400 * 2 + 64;
  static constexpr size_t H4  = H3 + (size_t)RING * 128 * 256 * 2 + 64;
  static constexpr size_t PK1 = H4 + (size_t)RING * 128 * 256 * 2 + 64; // f16 [TB][4NJ][KPAD]
  static constexpr size_t PK2 = PK1 + (size_t)TB1 * 32 * 704  * 2;
  static constexpr size_t PK3 = PK2 + (size_t)TB2 * 16 * 1056 * 2;
  static constexpr size_t PK4 = PK3 + (size_t)TB3 * 32 * 672  * 2;
  static constexpr size_t BAR = PK4 + (size_t)TB4 * 32 * 512  * 2;   // 8 KB sync area
  static constexpr size_t ZERO= BAR + 8192;                          // zeroed h[-1] region
  static constexpr size_t END = ZERO + 163840;                       // 128*640+slack f16
};
// U[0..511]: per-block arrival slots; U[512 + rep*64 + l]: rel[l] replicas

struct KParams {
  const float *x;
  const float *k1, *r1, *b1, *k2, *r2, *b2, *k3, *r3, *b3, *k4, *r4, *b4;
  const float *wd1, *bd1, *wd2, *bd2, *wd3, *bd3, *wd4, *bd4, *wd5, *bd5, *wd6, *bd6;
  float *out;
  char *ws;
};

__device__ __forceinline__ float sigm(float v) { return 1.f / (1.f + expf(-v)); }

// ---- agent-scope (cross-XCD coherent) primitives: flags + h publish ----
__device__ __forceinline__ uint64_t c_load8(const void* p) {
  return __hip_atomic_load((const uint64_t*)p, __ATOMIC_RELAXED, __HIP_MEMORY_SCOPE_AGENT);
}
__device__ __forceinline__ void c_store8(void* p, uint64_t v) {
  __hip_atomic_store((uint64_t*)p, v, __ATOMIC_RELAXED, __HIP_MEMORY_SCOPE_AGENT);
}
__device__ __forceinline__ unsigned short c_load2(const void* p) {
  return __hip_atomic_load((const unsigned short*)p, __ATOMIC_RELAXED, __HIP_MEMORY_SCOPE_AGENT);
}
__device__ __forceinline__ unsigned u_load(const unsigned* p) {
  return __hip_atomic_load(p, __ATOMIC_RELAXED, __HIP_MEMORY_SCOPE_AGENT);
}
__device__ __forceinline__ void u_store(unsigned* p, unsigned v) {
  __hip_atomic_store(p, v, __ATOMIC_RELAXED, __HIP_MEMORY_SCOPE_AGENT);
}
__device__ __forceinline__ void acq_fence() {
  __builtin_amdgcn_fence(__ATOMIC_ACQUIRE, "agent");
}

// ---------------- per-layer control block: publish watermark rel[lidx] ----------------
template<int NBLK>
__device__ void control_role(unsigned* U, int first, int lidx) {
  const int tid = threadIdx.x;
  int cand = 1;
  while (cand <= TSTEPS) {
    unsigned v = (tid < NBLK) ? u_load(&U[first + tid]) : 0xFFFFFFFFu;
    if (__syncthreads_and((int)(v >= (unsigned)cand))) {
      if (tid < 16) u_store(&U[512 + tid * 64 + lidx], (unsigned)cand);
      ++cand;
    }
  }
}

// ---------------- weight prepack: pack[blk][n][k], n = gate*NJ + jj, f16, zero-padded K ----------------
__device__ void prepack_layer(const float* __restrict__ gk, const float* __restrict__ gr,
                              f16* __restrict__ pack, int DIN, int H, int NJ, int KPAD,
                              int TB, int gtid, int gstr) {
  const int KREAL = DIN + H;
  const int NGC = 4 * NJ;
  const long total = (long)TB * NGC * KPAD;
  for (long e = gtid; e < total; e += gstr) {
    const int  k   = (int)(e % KPAD);
    const long r   = e / KPAD;
    const int  n   = (int)(r % NGC);
    const int  blk = (int)(r / NGC);
    const int  g   = n / NJ, jj = n % NJ;
    const int  j   = blk * NJ + jj;
    float v = 0.f;
    if (k < DIN)        v = gk[(size_t)k * 4 * H + (size_t)g * H + j];
    else if (k < KREAL) v = gr[(size_t)(k - DIN) * 4 * H + (size_t)g * H + j];
    pack[e] = (f16)v;
  }
}

// ---------------- MFMA LSTM layer role ----------------
// FETCH(buf, chunk): A-fragment loads for one chunk of C ksteps.
// Big path (RING==TSTEPS): PLAIN cached uint4 loads — h-ring addresses are
// write-once per run, so cold-miss L2 fills are coherent (validated r3) and
// redundant same-XCD reads become L2 hits. Fallback path: sc1 8B loads.
#define FETCH(PP, CC) do { \
  _Pragma("unroll") \
  for (int ii_ = 0; ii_ < C; ++ii_) { \
    const int ks_ = (CC) * C + ii_; \
    if (ks_ < KS) { \
      const int k_ = ks_ * 32 + kg; \
      _Pragma("unroll") \
      for (int m_ = 0; m_ < 2; ++m_) { \
        const int bmv_ = m_ ? bm1 : bm0; \
        uint4 v_ = make_uint4(0u, 0u, 0u, 0u); \
        if constexpr (SEQM) { \
          if (k_ < DIN)        v_ = *(const uint4*)(inP + (size_t)bmv_ * DIN + k_); \
          else if (k_ < KREAL) v_ = *(const uint4*)(inH + (size_t)bmv_ * H + (k_ - DIN)); \
        } else { \
          if (k_ < DIN) { \
            const f16* p_ = inP + (size_t)bmv_ * DIN + k_; \
            if constexpr (SEQIN) { \
              ((uint64_t*)&v_)[0] = *(const uint64_t*)p_; \
              ((uint64_t*)&v_)[1] = *(const uint64_t*)(p_ + 4); \
            } else { \
              ((uint64_t*)&v_)[0] = c_load8(p_); \
              ((uint64_t*)&v_)[1] = c_load8(p_ + 4); \
            } \
          } else if (k_ < KREAL) { \
            const f16* p_ = inH + (size_t)bmv_ * H + (k_ - DIN); \
            ((uint64_t*)&v_)[0] = c_load8(p_); \
            ((uint64_t*)&v_)[1] = c_load8(p_ + 4); \
          } \
        } \
        ab[PP][ii_][m_] = v_; \
      } \
    } \
  } \
} while (0)

// COMPUTE(buf, chunk): B-fragments from LDS + MFMAs for one chunk
#define COMPUTE(PP, CC) do { \
  _Pragma("unroll") \
  for (int ii_ = 0; ii_ < C; ++ii_) { \
    const int ks_ = (CC) * C + ii_; \
    if (ks_ < KS) { \
      const int kb_ = ks_ * 32; \
      h8v bf_[NTI]; \
      _Pragma("unroll") \
      for (int nt_ = 0; nt_ < NTI; ++nt_) \
        bf_[nt_] = *(const h8v*)(wlds + (size_t)(nt_ * 16 + l15) * WROW + kb_ + kg); \
      _Pragma("unroll") \
      for (int m_ = 0; m_ < 2; ++m_) { \
        union { uint4 u; h8v v; } af_; \
        af_.u = ab[PP][ii_][m_]; \
        _Pragma("unroll") \
        for (int nt_ = 0; nt_ < NTI; ++nt_) \
          acc[m_][nt_] = __builtin_amdgcn_mfma_f32_16x16x32_f16(af_.v, bf_[nt_], acc[m_][nt_], 0, 0, 0); \
      } \
    } \
  } \
} while (0)

// deferred own-peer wait: placed just before the first h-containing chunk
#define WAITOWN do { \
  if (tid == 0) { while (rcO < t) rcO = (int)u_load(&relp[LIDX]); } \
  __syncthreads(); \
} while (0)

template<int DIN, int H, int NJ, int LIDX, bool SEQIN, int RING>
__device__ void lstm_role(int blk, int bid, const f16* lo_base, f16* ownH,
                          const f16* pack, const float* __restrict__ gbias,
                          const f16* zreg, char* smem, unsigned* U) {
  constexpr bool SEQM = (RING == TSTEPS);
  constexpr int KREAL = DIN + H;
  constexpr int KS    = (KREAL + 31) / 32;
  constexpr int KPAD  = KS * 32;
  constexpr int NGC   = 4 * NJ;
  constexpr int NTI   = NGC / 16;          // N-tiles (1 or 2)
  constexpr int WROW  = KPAD + 8;          // weight LDS row (f16)
  constexpr int ZROW  = 132;               // z LDS row (f32)
  constexpr int C     = 6;                 // ksteps per chunk
  constexpr int NC    = (KS + C - 1) / C;
  constexpr int KSX   = DIN / 32;          // ksteps strictly below this are pure-x
  constexpr int CH    = KSX / C;           // first chunk that may touch own-h
  static_assert(NC <= 6, "NC");
  static_assert(CH <= NC - 1, "CH");
  static_assert(NGC % 16 == 0 && (DIN % 8) == 0 && (KREAL % 8) == 0, "geom");

  const int tid  = threadIdx.x;
  const int w    = tid >> 6, lane = tid & 63;
  const int l15  = lane & 15;
  const int kg   = (lane >> 4) * 8;
  const int bm0  = w * 32 + l15;
  const int bm1  = bm0 + 16;

  f16*   wlds = (f16*)smem;
  float* z    = (float*)(smem + (size_t)NGC * WROW * 2);

  // ---- load this block's weights to LDS once ----
  {
    const f16* src = pack + (size_t)blk * NGC * KPAD;
    constexpr int RU = KPAD / 8;
    for (int u = tid; u < NGC * RU; u += NT) {
      const int n = u / RU, k8 = u % RU;
      *(uint4*)(wlds + (size_t)n * WROW + k8 * 8) =
          *(const uint4*)(src + (size_t)n * KPAD + k8 * 8);
    }
  }
  __syncthreads();

  // ---- epilogue ownership: thread -> (batch be, 4 consecutive j) => one 8B store ----
  constexpr int JG = NJ / 4;               // j-groups per batch (2 or 1)
  const int be  = tid / JG;                // batch index
  const int g4  = tid % JG;                // which j-group
  const bool epi = (tid < 128 * JG);
  const int j0  = blk * NJ + g4 * 4;
  f32x4 bias4[4] = {};
  if (epi) {
    #pragma unroll
    for (int g = 0; g < 4; ++g) bias4[g] = *(const f32x4*)(gbias + (size_t)g * H + j0);
  }
  float cst[4] = {0.f, 0.f, 0.f, 0.f};

  const unsigned* relp = &U[512 + (bid & 15) * 64];
  int rcI = 0, rcO = 0, rcD = 0;
  (void)rcI; (void)rcD;

  for (int t = 0; t < TSTEPS; ++t) {
    // ---- top wait: prev-layer panel + ring slot (+ own peers only if CH==0) ----
    if (tid == 0) {
      for (;;) {
        bool ok = true;
        if constexpr (CH == 0) ok = (rcO >= t);
        if constexpr (LIDX > 0) ok = ok && (rcI >= t + 1);
        if constexpr (!SEQM && LIDX < 3) ok = ok && (rcD >= t - (RING - 1));
        if (ok) break;
        if constexpr (LIDX > 0) rcI = (int)u_load(&relp[LIDX - 1]);
        if constexpr (CH == 0) rcO = (int)u_load(&relp[LIDX]);
        if constexpr (!SEQM && LIDX < 3) rcD = (int)u_load(&relp[LIDX + 1]);
      }
    }
    __syncthreads();

    const f16* inP = SEQIN ? lo_base + (size_t)t * DIN * BATCH
                           : lo_base + (size_t)(t & (RING - 1)) * DIN * BATCH;
    const f16* inH = (t == 0) ? zreg
                              : ownH + (size_t)((t - 1) & (RING - 1)) * H * BATCH;

    f32x4 acc[2][NTI];
    {
      const f32x4 zz = {0.f, 0.f, 0.f, 0.f};
      #pragma unroll
      for (int m_ = 0; m_ < 2; ++m_)
        #pragma unroll
        for (int nt_ = 0; nt_ < NTI; ++nt_) acc[m_][nt_] = zz;
    }

    uint4 ab[3][C][2];

    // ---- software-pipelined K loop; own-peer wait deferred to first h chunk ----
    FETCH(0, 0);
    if constexpr (NC > 1) { if constexpr (CH == 1) WAITOWN; FETCH(1, 1); }
    if constexpr (NC > 2) { if constexpr (CH == 2) WAITOWN; FETCH(2, 2); }
    COMPUTE(0, 0);
    if constexpr (NC > 1) { if constexpr (NC > 3) { if constexpr (CH == 3) WAITOWN; FETCH(0, 3); } COMPUTE(1, 1); }
    if constexpr (NC > 2) { if constexpr (NC > 4) { if constexpr (CH == 4) WAITOWN; FETCH(1, 4); } COMPUTE(2, 2); }
    if constexpr (NC > 3) { if constexpr (NC > 5) { if constexpr (CH == 5) WAITOWN; FETCH(2, 5); } COMPUTE(0, 3); }
    if constexpr (NC > 4) COMPUTE(1, 4);
    if constexpr (NC > 5) COMPUTE(2, 5);

    // ---- D fragments -> z[gatecol][batch] in LDS ----
    #pragma unroll
    for (int m_ = 0; m_ < 2; ++m_)
      #pragma unroll
      for (int nt_ = 0; nt_ < NTI; ++nt_)
        *(f32x4*)(z + (size_t)(nt_ * 16 + l15) * ZROW + w * 32 + m_ * 16 + (lane >> 4) * 4) =
            acc[m_][nt_];
    __syncthreads();

    // ---- epilogue: gates, state, ONE coalesced 8B sc1 h store per thread ----
    if (epi) {
      float vi[4], vf[4], vg[4], vo[4];
      #pragma unroll
      for (int q = 0; q < 4; ++q) {
        const int nn = g4 * 4 + q;
        vi[q] = z[(size_t)(0 * NJ + nn) * ZROW + be];
        vf[q] = z[(size_t)(1 * NJ + nn) * ZROW + be];
        vg[q] = z[(size_t)(2 * NJ + nn) * ZROW + be];
        vo[q] = z[(size_t)(3 * NJ + nn) * ZROW + be];
      }
      union { f16 h[4]; uint64_t u; } o;
      #pragma unroll
      for (int q = 0; q < 4; ++q) {
        const float ig = sigm(vi[q] + bias4[0][q]);
        const float fg = sigm(vf[q] + bias4[1][q]);
        const float gg = tanhf(vg[q] + bias4[2][q]);
        const float og = sigm(vo[q] + bias4[3][q]);
        cst[q] = fg * cst[q] + ig * gg;
        o.h[q] = (f16)(og * tanhf(cst[q]));
      }
      c_store8(ownH + (size_t)(t & (RING - 1)) * H * BATCH + (size_t)be * H + j0, o.u);
    }
    asm volatile("s_waitcnt vmcnt(0)" ::: "memory");
    __syncthreads();
    if (tid == 0) u_store(&U[bid], (unsigned)(t + 1));
  }
}
#undef FETCH
#undef COMPUTE
#undef WAITOWN

// ---------------- dense head ----------------
__device__ void dense_stage(const float* in, float* outb,
                            const float* __restrict__ w, const float* __restrict__ bias,
                            int din, int dout, bool relu) {
  for (int jc = threadIdx.x; jc < dout; jc += NT) {
    float s = bias[jc];
    for (int d = 0; d < din; ++d) s += in[d] * w[(size_t)d * dout + jc];
    outb[jc] = relu ? fmaxf(s, 0.f) : s;
  }
  __syncthreads();
}

constexpr size_t cmax(size_t a, size_t b) { return a > b ? a : b; }
constexpr size_t wlz(int NGC, int KPAD) {
  return (size_t)NGC * (KPAD + 8) * 2 + (size_t)NGC * 132 * 4;
}
static constexpr size_t SMEM_BYTES =
    cmax(cmax(wlz(32, 704), wlz(16, 1056)),
         cmax(cmax(wlz(32, 672), wlz(32, 512)), (size_t)4096));
static_assert(SMEM_BYTES <= 65536, "LDS");

// ---------------- fused cooperative kernel ----------------
template<int RING>
__global__ __launch_bounds__(NT, 1) void fused_kernel(KParams p) {
  using L = WS<RING>;
  cg::grid_group grid = cg::this_grid();
  __shared__ __attribute__((aligned(16))) char smem[SMEM_BYTES];

  char* ws = p.ws;
  unsigned* U = (unsigned*)(ws + L::BAR);
  const f16* zreg = (const f16*)(ws + L::ZERO);
  const int tid  = threadIdx.x;
  const int bid  = blockIdx.x;
  const int gtid = bid * NT + tid;
  const int gstr = NGRID * NT;

  // ---- phase 0a: prepack weights (f16, [blk][gatecol][k], K zero-padded to x32) ----
  prepack_layer(p.k1, p.r1, (f16*)(ws + L::PK1), 64,  640, 8, 704,  TB1, gtid, gstr);
  prepack_layer(p.k2, p.r2, (f16*)(ws + L::PK2), 640, 400, 4, 1056, TB2, gtid, gstr);
  prepack_layer(p.k3, p.r3, (f16*)(ws + L::PK3), 400, 256, 8, 672,  TB3, gtid, gstr);
  prepack_layer(p.k4, p.r4, (f16*)(ws + L::PK4), 256, 256, 8, 512,  TB4, gtid, gstr);

  // ---- phase 0b: x [128][512][64] f32 -> xT [512][128][64] f16 (batch-major) ----
  {
    f16* xT = (f16*)(ws + L::XT);
    const long total = (long)TSTEPS * BATCH * 8;
    for (long u = gtid; u < total; u += gstr) {
      const int  d8 = (int)(u & 7);
      const long r  = u >> 3;
      const int  b  = (int)(r & (BATCH - 1));
      const int  t  = (int)(r >> 7);
      const float* src = p.x + ((size_t)b * TSTEPS + t) * 64 + d8 * 8;
      const float4 v0 = *(const float4*)src;
      const float4 v1 = *(const float4*)(src + 4);
      h8v o;
      o[0] = (f16)v0.x; o[1] = (f16)v0.y; o[2] = (f16)v0.z; o[3] = (f16)v0.w;
      o[4] = (f16)v1.x; o[5] = (f16)v1.y; o[6] = (f16)v1.z; o[7] = (f16)v1.w;
      *(h8v*)(xT + ((size_t)t * BATCH + b) * 64 + d8 * 8) = o;
    }
  }

  grid.sync();   // publish packs/xT device-wide
  acq_fence();   // once per run: drop any stale ring lines from a prior launch

  // ---- phase 1: dataflow-pipelined 4-layer LSTM scan (MFMA) ----
  constexpr int TRB2 = TB1, TRB3 = TB1 + TB2, TRB4 = TB1 + TB2 + TB3;
  if (bid >= TNB) {
    const int l = bid - TNB;
    if (l == 0)      control_role<TB1>(U, 0,    0);
    else if (l == 1) control_role<TB2>(U, TRB2, 1);
    else if (l == 2) control_role<TB3>(U, TRB3, 2);
    else             control_role<TB4>(U, TRB4, 3);
  } else if (bid < TRB2) {
    lstm_role< 64, 640, 8, 0, true , RING>(bid, bid, (const f16*)(ws + L::XT),
        (f16*)(ws + L::H1), (const f16*)(ws + L::PK1), p.b1, zreg, smem, U);
  } else if (bid < TRB3) {
    lstm_role<640, 400, 4, 1, false, RING>(bid - TRB2, bid, (const f16*)(ws + L::H1),
        (f16*)(ws + L::H2), (const f16*)(ws + L::PK2), p.b2, zreg, smem, U);
  } else if (bid < TRB4) {
    lstm_role<400, 256, 8, 2, false, RING>(bid - TRB3, bid, (const f16*)(ws + L::H2),
        (f16*)(ws + L::H3), (const f16*)(ws + L::PK3), p.b3, zreg, smem, U);
  } else {
    lstm_role<256, 256, 8, 3, false, RING>(bid - TRB4, bid, (const f16*)(ws + L::H3),
        (f16*)(ws + L::H4), (const f16*)(ws + L::PK4), p.b4, zreg, smem, U);
  }

  // ---- phase 2: dense head ----
  if (bid < BATCH) {
    if (tid == 0) {
      const unsigned* relp = &U[512 + (bid & 15) * 64];
      while ((int)u_load(&relp[3]) < TSTEPS) {}
    }
    __syncthreads();
    const int b = bid;
    float* A = (float*)smem;
    float* B = (float*)smem + 512;
    const f16* h4 = (const f16*)(ws + L::H4)
                  + (size_t)((TSTEPS - 1) & (RING - 1)) * 256 * BATCH + (size_t)b * 256;
    for (int d = tid; d < 256; d += NT) {
      union { unsigned short u; f16 h; } cc;
      cc.u = c_load2(h4 + d);
      A[d] = (float)cc.h;
    }
    __syncthreads();
    dense_stage(A, B, p.wd1, p.bd1, 256, 512, true);
    dense_stage(B, A, p.wd2, p.bd2, 512, 256, true);
    dense_stage(A, B, p.wd3, p.bd3, 256, 128, true);
    dense_stage(B, A, p.wd4, p.bd4, 128, 64,  true);
    dense_stage(A, B, p.wd5, p.bd5, 64,  16,  true);
    dense_stage(B, A, p.wd6, p.bd6, 16,  3,   false);
    if (tid == 0) {
      float z0 = A[0], z1 = A[1], z2 = A[2];
      float m  = fmaxf(fmaxf(z0, z1), z2);
      float e0 = expf(z0 - m), e1 = expf(z1 - m), e2 = expf(z2 - m);
      float s  = e0 + e1 + e2;
      p.out[b * 3 + 0] = e0 / s;
      p.out[b * 3 + 1] = e1 / s;
      p.out[b * 3 + 2] = e2 / s;
    }
  }
}

// ---------------- launch ----------------
extern "C" void kernel_launch(void* const* d_in, const int* in_sizes, int n_in,
                              void* d_out, int out_size, void* d_ws, size_t ws_size,
                              hipStream_t stream) {
  (void)in_sizes; (void)n_in; (void)out_size;
  KParams prm;
  prm.x  = (const float*)d_in[0];
  prm.k1 = (const float*)d_in[1];  prm.r1 = (const float*)d_in[2];  prm.b1 = (const float*)d_in[3];
  prm.k2 = (const float*)d_in[4];  prm.r2 = (const float*)d_in[5];  prm.b2 = (const float*)d_in[6];
  prm.k3 = (const float*)d_in[7];  prm.r3 = (const float*)d_in[8];  prm.b3 = (const float*)d_in[9];
  prm.k4 = (const float*)d_in[10]; prm.r4 = (const float*)d_in[11]; prm.b4 = (const float*)d_in[12];
  prm.wd1 = (const float*)d_in[13]; prm.bd1 = (const float*)d_in[14];
  prm.wd2 = (const float*)d_in[15]; prm.bd2 = (const float*)d_in[16];
  prm.wd3 = (const float*)d_in[17]; prm.bd3 = (const float*)d_in[18];
  prm.wd4 = (const float*)d_in[19]; prm.bd4 = (const float*)d_in[20];
  prm.wd5 = (const float*)d_in[21]; prm.bd5 = (const float*)d_in[22];
  prm.wd6 = (const float*)d_in[23]; prm.bd6 = (const float*)d_in[24];
  prm.out = (float*)d_out;
  prm.ws  = (char*)d_ws;

  const bool big = ws_size >= WS<TSTEPS>::END;
  const size_t bar_off = big ? WS<TSTEPS>::BAR : WS<4>::BAR;
  // zero the sync area AND the h[-1] zero-region (contiguous)
  hipMemsetAsync((char*)d_ws + bar_off, 0, 8192 + 163840, stream);

  void* args[] = { &prm };
  if (big) {
    hipLaunchCooperativeKernel((void*)fused_kernel<TSTEPS>, dim3(NGRID), dim3(NT),
                               args, 0, stream);
  } else {
    hipLaunchCooperativeKernel((void*)fused_kernel<4>, dim3(NGRID), dim3(NT),
                               args, 0, stream);
  }
}

// Round 8
// 4854.305 us; speedup vs baseline: 1.3560x; 1.0306x over previous
//
#include <hip/hip_runtime.h>
#include <hip/hip_cooperative_groups.h>
#include <cstdint>
#include <cstddef>

namespace cg = cooperative_groups;

typedef _Float16 f16;
typedef _Float16 h8v  __attribute__((ext_vector_type(8)));
typedef float    f32x4 __attribute__((ext_vector_type(4)));

static constexpr int BATCH  = 128;
static constexpr int TSTEPS = 512;
static constexpr int NT     = 256;

// worker blocks per layer (NJ = hidden units per block: 8,4,8,8)
static constexpr int TB1 = 80, TB2 = 100, TB3 = 32, TB4 = 32;
static constexpr int TNB   = TB1 + TB2 + TB3 + TB4;   // 244
static constexpr int NGRID = TNB + 4;                 // + 4 control blocks

// ---------------- workspace layout (byte offsets) ----------------
// all h tensors batch-major: [slot][b][j]  (f16)
template<int RING> struct WS {
  static constexpr size_t XT  = 0;                                   // f16 [512][128][64]
  static constexpr size_t H1  = XT + 512ull * 128 * 64 * 2;          // f16 [RING][128][640]
  static constexpr size_t H2  = H1 + (size_t)RING * 128 * 640 * 2 + 64;
  static constexpr size_t H3  = H2 + (size_t)RING * 128 * 400 * 2 + 64;
  static constexpr size_t H4  = H3 + (size_t)RING * 128 * 256 * 2 + 64;
  static constexpr size_t PK1 = H4 + (size_t)RING * 128 * 256 * 2 + 64; // f16 [TB][4NJ][KPAD]
  static constexpr size_t PK2 = PK1 + (size_t)TB1 * 32 * 704  * 2;
  static constexpr size_t PK3 = PK2 + (size_t)TB2 * 16 * 1056 * 2;
  static constexpr size_t PK4 = PK3 + (size_t)TB3 * 32 * 672  * 2;
  static constexpr size_t BAR = PK4 + (size_t)TB4 * 32 * 512  * 2;   // 8 KB sync area
  static constexpr size_t ZERO= BAR + 8192;                          // zeroed h[-1] region
  static constexpr size_t END = ZERO + 163840;                       // 128*640+slack f16
};
// U[4*bid + w] (0..975): per-WAVE step flags
// U[1024 + rep*64 + lidx*4 + w]: per-(layer,wave) watermark replicas, rep 0..15

struct KParams {
  const float *x;
  const float *k1, *r1, *b1, *k2, *r2, *b2, *k3, *r3, *b3, *k4, *r4, *b4;
  const float *wd1, *bd1, *wd2, *bd2, *wd3, *bd3, *wd4, *bd4, *wd5, *bd5, *wd6, *bd6;
  float *out;
  char *ws;
};

__device__ __forceinline__ float sigm(float v) { return 1.f / (1.f + expf(-v)); }

// ---- agent-scope (cross-XCD coherent) primitives: flags + h publish ----
__device__ __forceinline__ uint64_t c_load8(const void* p) {
  return __hip_atomic_load((const uint64_t*)p, __ATOMIC_RELAXED, __HIP_MEMORY_SCOPE_AGENT);
}
__device__ __forceinline__ void c_store8(void* p, uint64_t v) {
  __hip_atomic_store((uint64_t*)p, v, __ATOMIC_RELAXED, __HIP_MEMORY_SCOPE_AGENT);
}
__device__ __forceinline__ unsigned short c_load2(const void* p) {
  return __hip_atomic_load((const unsigned short*)p, __ATOMIC_RELAXED, __HIP_MEMORY_SCOPE_AGENT);
}
__device__ __forceinline__ unsigned u_load(const unsigned* p) {
  return __hip_atomic_load(p, __ATOMIC_RELAXED, __HIP_MEMORY_SCOPE_AGENT);
}
__device__ __forceinline__ void u_store(unsigned* p, unsigned v) {
  __hip_atomic_store(p, v, __ATOMIC_RELAXED, __HIP_MEMORY_SCOPE_AGENT);
}
__device__ __forceinline__ void acq_fence() {
  __builtin_amdgcn_fence(__ATOMIC_ACQUIRE, "agent");
}

// ---------------- per-layer control block: 4 independent wave-engines ----------------
// wave w publishes watermark rel[lidx][w] = min step completed by all layer blocks' wave w
template<int NBLK>
__device__ void control_role(unsigned* U, int first, int lidx) {
  const int w = threadIdx.x >> 6, lane = threadIdx.x & 63;
  int cand = 1;
  while (cand <= TSTEPS) {
    unsigned v0 = (lane < NBLK)      ? u_load(&U[4 * (first + lane) + w])      : 0xFFFFFFFFu;
    unsigned v1 = (lane + 64 < NBLK) ? u_load(&U[4 * (first + lane + 64) + w]) : 0xFFFFFFFFu;
    unsigned v = v0 < v1 ? v0 : v1;
    if (__all((int)(v >= (unsigned)cand))) {
      if (lane < 16) u_store(&U[1024 + lane * 64 + lidx * 4 + w], (unsigned)cand);
      ++cand;
    }
  }
}

// ---------------- weight prepack: pack[blk][n][k], n = gate*NJ + jj, f16, zero-padded K ----------------
__device__ void prepack_layer(const float* __restrict__ gk, const float* __restrict__ gr,
                              f16* __restrict__ pack, int DIN, int H, int NJ, int KPAD,
                              int TB, int gtid, int gstr) {
  const int KREAL = DIN + H;
  const int NGC = 4 * NJ;
  const long total = (long)TB * NGC * KPAD;
  for (long e = gtid; e < total; e += gstr) {
    const int  k   = (int)(e % KPAD);
    const long r   = e / KPAD;
    const int  n   = (int)(r % NGC);
    const int  blk = (int)(r / NGC);
    const int  g   = n / NJ, jj = n % NJ;
    const int  j   = blk * NJ + jj;
    float v = 0.f;
    if (k < DIN)        v = gk[(size_t)k * 4 * H + (size_t)g * H + j];
    else if (k < KREAL) v = gr[(size_t)(k - DIN) * 4 * H + (size_t)g * H + j];
    pack[e] = (f16)v;
  }
}

// ---------------- MFMA LSTM layer role (fully per-wave step loop) ----------------
// FETCH(buf, chunk): A-fragment loads for one chunk of C ksteps.
// Big path (RING==TSTEPS): PLAIN cached uint4 loads — h-ring addresses are
// write-once per run, so cold-miss L2 fills are coherent (validated r3) and
// redundant same-XCD reads become L2 hits. Fallback path: sc1 8B loads.
#define FETCH(PP, CC) do { \
  _Pragma("unroll") \
  for (int ii_ = 0; ii_ < C; ++ii_) { \
    const int ks_ = (CC) * C + ii_; \
    if (ks_ < KS) { \
      const int k_ = ks_ * 32 + kg; \
      _Pragma("unroll") \
      for (int m_ = 0; m_ < 2; ++m_) { \
        const int bmv_ = m_ ? bm1 : bm0; \
        uint4 v_ = make_uint4(0u, 0u, 0u, 0u); \
        if constexpr (SEQM) { \
          if (k_ < DIN)        v_ = *(const uint4*)(inP + (size_t)bmv_ * DIN + k_); \
          else if (k_ < KREAL) v_ = *(const uint4*)(inH + (size_t)bmv_ * H + (k_ - DIN)); \
        } else { \
          if (k_ < DIN) { \
            const f16* p_ = inP + (size_t)bmv_ * DIN + k_; \
            if constexpr (SEQIN) { \
              ((uint64_t*)&v_)[0] = *(const uint64_t*)p_; \
              ((uint64_t*)&v_)[1] = *(const uint64_t*)(p_ + 4); \
            } else { \
              ((uint64_t*)&v_)[0] = c_load8(p_); \
              ((uint64_t*)&v_)[1] = c_load8(p_ + 4); \
            } \
          } else if (k_ < KREAL) { \
            const f16* p_ = inH + (size_t)bmv_ * H + (k_ - DIN); \
            ((uint64_t*)&v_)[0] = c_load8(p_); \
            ((uint64_t*)&v_)[1] = c_load8(p_ + 4); \
          } \
        } \
        ab[PP][ii_][m_] = v_; \
      } \
    } \
  } \
} while (0)

// COMPUTE(buf, chunk): B-fragments from LDS + MFMAs for one chunk
#define COMPUTE(PP, CC) do { \
  _Pragma("unroll") \
  for (int ii_ = 0; ii_ < C; ++ii_) { \
    const int ks_ = (CC) * C + ii_; \
    if (ks_ < KS) { \
      const int kb_ = ks_ * 32; \
      h8v bf_[NTI]; \
      _Pragma("unroll") \
      for (int nt_ = 0; nt_ < NTI; ++nt_) \
        bf_[nt_] = *(const h8v*)(wlds + (size_t)(nt_ * 16 + l15) * WROW + kb_ + kg); \
      _Pragma("unroll") \
      for (int m_ = 0; m_ < 2; ++m_) { \
        union { uint4 u; h8v v; } af_; \
        af_.u = ab[PP][ii_][m_]; \
        _Pragma("unroll") \
        for (int nt_ = 0; nt_ < NTI; ++nt_) \
          acc[m_][nt_] = __builtin_amdgcn_mfma_f32_16x16x32_f16(af_.v, bf_[nt_], acc[m_][nt_], 0, 0, 0); \
      } \
    } \
  } \
} while (0)

// deferred own-peer wait (per-wave): lane 0 polls own-layer wave-w watermark
#define WAITOWN do { \
  bool c_ = (lane != 0) || (rcO >= t); \
  while (!__all((int)c_)) { \
    if (!c_) { rcO = (int)u_load(&relp[LIDX * 4 + w]); c_ = (rcO >= t); } \
  } \
} while (0)

template<int DIN, int H, int NJ, int LIDX, bool SEQIN, int RING>
__device__ void lstm_role(int blk, int bid, const f16* lo_base, f16* ownH,
                          const f16* pack, const float* __restrict__ gbias,
                          const f16* zreg, char* smem, unsigned* U) {
  constexpr bool SEQM = (RING == TSTEPS);
  constexpr int KREAL = DIN + H;
  constexpr int KS    = (KREAL + 31) / 32;
  constexpr int KPAD  = KS * 32;
  constexpr int NGC   = 4 * NJ;
  constexpr int NTI   = NGC / 16;          // N-tiles (1 or 2)
  constexpr int WROW  = KPAD + 8;          // weight LDS row (f16)
  constexpr int ZROW  = 132;               // z LDS row (f32)
  constexpr int C     = 6;                 // ksteps per chunk
  constexpr int NC    = (KS + C - 1) / C;
  constexpr int KSX   = DIN / 32;          // ksteps strictly below this are pure-x
  constexpr int CH    = KSX / C;           // first chunk that may touch own-h
  static_assert(NC <= 6, "NC");
  static_assert(CH <= NC - 1, "CH");
  static_assert(NGC % 16 == 0 && (DIN % 8) == 0 && (KREAL % 8) == 0, "geom");

  const int tid  = threadIdx.x;
  const int w    = tid >> 6, lane = tid & 63;
  const int l15  = lane & 15;
  const int kg   = (lane >> 4) * 8;
  const int bm0  = w * 32 + l15;
  const int bm1  = bm0 + 16;

  f16*   wlds = (f16*)smem;
  float* z    = (float*)(smem + (size_t)NGC * WROW * 2);

  // ---- load this block's weights to LDS once ----
  {
    const f16* src = pack + (size_t)blk * NGC * KPAD;
    constexpr int RU = KPAD / 8;
    for (int u = tid; u < NGC * RU; u += NT) {
      const int n = u / RU, k8 = u % RU;
      *(uint4*)(wlds + (size_t)n * WROW + k8 * 8) =
          *(const uint4*)(src + (size_t)n * KPAD + k8 * 8);
    }
  }
  __syncthreads();   // only barrier: weights visible to all waves

  // ---- per-wave epilogue ownership: lane -> (batch be in wave range, 4 consecutive j) ----
  constexpr int JW = NJ / 4;               // j-groups per batch (2 or 1)
  const int be  = 32 * w + lane / JW;
  const int jg  = lane % JW;
  const bool epi = (lane < 32 * JW);
  const int j0  = blk * NJ + jg * 4;
  f32x4 bias4[4] = {};
  if (epi) {
    #pragma unroll
    for (int g = 0; g < 4; ++g) bias4[g] = *(const f32x4*)(gbias + (size_t)g * H + j0);
  }
  float cst[4] = {0.f, 0.f, 0.f, 0.f};

  const unsigned* relp = &U[1024 + (bid & 15) * 64];
  int rcI = 0, rcO = 0, rcD = 0;
  (void)rcI; (void)rcD;

  for (int t = 0; t < TSTEPS; ++t) {
    // ---- per-wave dataflow wait: parallel lanes, no block barrier ----
    {
      bool c = true;
      if constexpr (LIDX > 0) { if (lane == 0) c = (rcI >= t + 1); }
      if constexpr (CH == 0)  { if (lane == 1) c = (rcO >= t); }
      if constexpr (!SEQM && LIDX < 3) { if (lane == 2) c = (rcD >= t - (RING - 1)); }
      while (!__all((int)c)) {
        if (!c) {
          if constexpr (LIDX > 0) {
            if (lane == 0) { rcI = (int)u_load(&relp[(LIDX - 1) * 4 + w]); c = (rcI >= t + 1); }
          }
          if constexpr (CH == 0) {
            if (lane == 1) { rcO = (int)u_load(&relp[LIDX * 4 + w]); c = (rcO >= t); }
          }
          if constexpr (!SEQM && LIDX < 3) {
            if (lane == 2) { rcD = (int)u_load(&relp[(LIDX + 1) * 4 + w]); c = (rcD >= t - (RING - 1)); }
          }
        }
      }
    }

    const f16* inP = SEQIN ? lo_base + (size_t)t * DIN * BATCH
                           : lo_base + (size_t)(t & (RING - 1)) * DIN * BATCH;
    const f16* inH = (t == 0) ? zreg
                              : ownH + (size_t)((t - 1) & (RING - 1)) * H * BATCH;

    f32x4 acc[2][NTI];
    {
      const f32x4 zz = {0.f, 0.f, 0.f, 0.f};
      #pragma unroll
      for (int m_ = 0; m_ < 2; ++m_)
        #pragma unroll
        for (int nt_ = 0; nt_ < NTI; ++nt_) acc[m_][nt_] = zz;
    }

    uint4 ab[3][C][2];

    // ---- software-pipelined K loop; own-peer wait deferred to first h chunk ----
    FETCH(0, 0);
    if constexpr (NC > 1) { if constexpr (CH == 1) WAITOWN; FETCH(1, 1); }
    if constexpr (NC > 2) { if constexpr (CH == 2) WAITOWN; FETCH(2, 2); }
    COMPUTE(0, 0);
    if constexpr (NC > 1) { if constexpr (NC > 3) { if constexpr (CH == 3) WAITOWN; FETCH(0, 3); } COMPUTE(1, 1); }
    if constexpr (NC > 2) { if constexpr (NC > 4) { if constexpr (CH == 4) WAITOWN; FETCH(1, 4); } COMPUTE(2, 2); }
    if constexpr (NC > 3) { if constexpr (NC > 5) { if constexpr (CH == 5) WAITOWN; FETCH(2, 5); } COMPUTE(0, 3); }
    if constexpr (NC > 4) COMPUTE(1, 4);
    if constexpr (NC > 5) COMPUTE(2, 5);

    // ---- D fragments -> z[gatecol][batch] in LDS (wave-disjoint columns) ----
    #pragma unroll
    for (int m_ = 0; m_ < 2; ++m_)
      #pragma unroll
      for (int nt_ = 0; nt_ < NTI; ++nt_)
        *(f32x4*)(z + (size_t)(nt_ * 16 + l15) * ZROW + w * 32 + m_ * 16 + (lane >> 4) * 4) =
            acc[m_][nt_];
    // (wave-internal LDS RAW: compiler-ordered lgkmcnt; columns are wave-local, no barrier)

    // ---- per-wave epilogue: gates, state, one coalesced 8B sc1 h store per lane ----
    if (epi) {
      float vi[4], vf[4], vg[4], vo[4];
      #pragma unroll
      for (int q = 0; q < 4; ++q) {
        const int nn = jg * 4 + q;
        vi[q] = z[(size_t)(0 * NJ + nn) * ZROW + be];
        vf[q] = z[(size_t)(1 * NJ + nn) * ZROW + be];
        vg[q] = z[(size_t)(2 * NJ + nn) * ZROW + be];
        vo[q] = z[(size_t)(3 * NJ + nn) * ZROW + be];
      }
      union { f16 h[4]; uint64_t u; } o;
      #pragma unroll
      for (int q = 0; q < 4; ++q) {
        const float ig = sigm(vi[q] + bias4[0][q]);
        const float fg = sigm(vf[q] + bias4[1][q]);
        const float gg = tanhf(vg[q] + bias4[2][q]);
        const float og = sigm(vo[q] + bias4[3][q]);
        cst[q] = fg * cst[q] + ig * gg;
        o.h[q] = (f16)(og * tanhf(cst[q]));
      }
      c_store8(ownH + (size_t)(t & (RING - 1)) * H * BATCH + (size_t)be * H + j0, o.u);
    }
    asm volatile("s_waitcnt vmcnt(0)" ::: "memory");      // per-wave drain (own stores only)
    if (lane == 0) u_store(&U[4 * bid + w], (unsigned)(t + 1));   // per-wave publish
  }
}
#undef FETCH
#undef COMPUTE
#undef WAITOWN

// ---------------- dense head ----------------
__device__ void dense_stage(const float* in, float* outb,
                            const float* __restrict__ w, const float* __restrict__ bias,
                            int din, int dout, bool relu) {
  for (int jc = threadIdx.x; jc < dout; jc += NT) {
    float s = bias[jc];
    for (int d = 0; d < din; ++d) s += in[d] * w[(size_t)d * dout + jc];
    outb[jc] = relu ? fmaxf(s, 0.f) : s;
  }
  __syncthreads();
}

constexpr size_t cmax(size_t a, size_t b) { return a > b ? a : b; }
constexpr size_t wlz(int NGC, int KPAD) {
  return (size_t)NGC * (KPAD + 8) * 2 + (size_t)NGC * 132 * 4;
}
static constexpr size_t SMEM_BYTES =
    cmax(cmax(wlz(32, 704), wlz(16, 1056)),
         cmax(cmax(wlz(32, 672), wlz(32, 512)), (size_t)4096));
static_assert(SMEM_BYTES <= 65536, "LDS");

// ---------------- fused cooperative kernel ----------------
template<int RING>
__global__ __launch_bounds__(NT, 1) void fused_kernel(KParams p) {
  using L = WS<RING>;
  cg::grid_group grid = cg::this_grid();
  __shared__ __attribute__((aligned(16))) char smem[SMEM_BYTES];

  char* ws = p.ws;
  unsigned* U = (unsigned*)(ws + L::BAR);
  const f16* zreg = (const f16*)(ws + L::ZERO);
  const int tid  = threadIdx.x;
  const int bid  = blockIdx.x;
  const int gtid = bid * NT + tid;
  const int gstr = NGRID * NT;

  // ---- phase 0a: prepack weights (f16, [blk][gatecol][k], K zero-padded to x32) ----
  prepack_layer(p.k1, p.r1, (f16*)(ws + L::PK1), 64,  640, 8, 704,  TB1, gtid, gstr);
  prepack_layer(p.k2, p.r2, (f16*)(ws + L::PK2), 640, 400, 4, 1056, TB2, gtid, gstr);
  prepack_layer(p.k3, p.r3, (f16*)(ws + L::PK3), 400, 256, 8, 672,  TB3, gtid, gstr);
  prepack_layer(p.k4, p.r4, (f16*)(ws + L::PK4), 256, 256, 8, 512,  TB4, gtid, gstr);

  // ---- phase 0b: x [128][512][64] f32 -> xT [512][128][64] f16 (batch-major) ----
  {
    f16* xT = (f16*)(ws + L::XT);
    const long total = (long)TSTEPS * BATCH * 8;
    for (long u = gtid; u < total; u += gstr) {
      const int  d8 = (int)(u & 7);
      const long r  = u >> 3;
      const int  b  = (int)(r & (BATCH - 1));
      const int  t  = (int)(r >> 7);
      const float* src = p.x + ((size_t)b * TSTEPS + t) * 64 + d8 * 8;
      const float4 v0 = *(const float4*)src;
      const float4 v1 = *(const float4*)(src + 4);
      h8v o;
      o[0] = (f16)v0.x; o[1] = (f16)v0.y; o[2] = (f16)v0.z; o[3] = (f16)v0.w;
      o[4] = (f16)v1.x; o[5] = (f16)v1.y; o[6] = (f16)v1.z; o[7] = (f16)v1.w;
      *(h8v*)(xT + ((size_t)t * BATCH + b) * 64 + d8 * 8) = o;
    }
  }

  grid.sync();   // publish packs/xT device-wide
  acq_fence();   // once per run: drop any stale ring lines from a prior launch

  // ---- phase 1: dataflow-pipelined 4-layer LSTM scan (MFMA, per-wave sync) ----
  constexpr int TRB2 = TB1, TRB3 = TB1 + TB2, TRB4 = TB1 + TB2 + TB3;
  if (bid >= TNB) {
    const int l = bid - TNB;
    if (l == 0)      control_role<TB1>(U, 0,    0);
    else if (l == 1) control_role<TB2>(U, TRB2, 1);
    else if (l == 2) control_role<TB3>(U, TRB3, 2);
    else             control_role<TB4>(U, TRB4, 3);
  } else if (bid < TRB2) {
    lstm_role< 64, 640, 8, 0, true , RING>(bid, bid, (const f16*)(ws + L::XT),
        (f16*)(ws + L::H1), (const f16*)(ws + L::PK1), p.b1, zreg, smem, U);
  } else if (bid < TRB3) {
    lstm_role<640, 400, 4, 1, false, RING>(bid - TRB2, bid, (const f16*)(ws + L::H1),
        (f16*)(ws + L::H2), (const f16*)(ws + L::PK2), p.b2, zreg, smem, U);
  } else if (bid < TRB4) {
    lstm_role<400, 256, 8, 2, false, RING>(bid - TRB3, bid, (const f16*)(ws + L::H2),
        (f16*)(ws + L::H3), (const f16*)(ws + L::PK3), p.b3, zreg, smem, U);
  } else {
    lstm_role<256, 256, 8, 3, false, RING>(bid - TRB4, bid, (const f16*)(ws + L::H3),
        (f16*)(ws + L::H4), (const f16*)(ws + L::PK4), p.b4, zreg, smem, U);
  }

  // ---- phase 2: dense head ----
  if (bid < BATCH) {
    if (tid < 64) {
      bool c = (tid >= 4);
      int rc = 0;
      while (!__all((int)c)) {
        if (!c) {
          rc = (int)u_load(&U[1024 + (bid & 15) * 64 + 3 * 4 + tid]);
          c = (rc >= TSTEPS);
        }
      }
    }
    __syncthreads();
    const int b = bid;
    float* A = (float*)smem;
    float* B = (float*)smem + 512;
    const f16* h4 = (const f16*)(ws + L::H4)
                  + (size_t)((TSTEPS - 1) & (RING - 1)) * 256 * BATCH + (size_t)b * 256;
    for (int d = tid; d < 256; d += NT) {
      union { unsigned short u; f16 h; } cc;
      cc.u = c_load2(h4 + d);
      A[d] = (float)cc.h;
    }
    __syncthreads();
    dense_stage(A, B, p.wd1, p.bd1, 256, 512, true);
    dense_stage(B, A, p.wd2, p.bd2, 512, 256, true);
    dense_stage(A, B, p.wd3, p.bd3, 256, 128, true);
    dense_stage(B, A, p.wd4, p.bd4, 128, 64,  true);
    dense_stage(A, B, p.wd5, p.bd5, 64,  16,  true);
    dense_stage(B, A, p.wd6, p.bd6, 16,  3,   false);
    if (tid == 0) {
      float z0 = A[0], z1 = A[1], z2 = A[2];
      float m  = fmaxf(fmaxf(z0, z1), z2);
      float e0 = expf(z0 - m), e1 = expf(z1 - m), e2 = expf(z2 - m);
      float s  = e0 + e1 + e2;
      p.out[b * 3 + 0] = e0 / s;
      p.out[b * 3 + 1] = e1 / s;
      p.out[b * 3 + 2] = e2 / s;
    }
  }
}

// ---------------- launch ----------------
extern "C" void kernel_launch(void* const* d_in, const int* in_sizes, int n_in,
                              void* d_out, int out_size, void* d_ws, size_t ws_size,
                              hipStream_t stream) {
  (void)in_sizes; (void)n_in; (void)out_size;
  KParams prm;
  prm.x  = (const float*)d_in[0];
  prm.k1 = (const float*)d_in[1];  prm.r1 = (const float*)d_in[2];  prm.b1 = (const float*)d_in[3];
  prm.k2 = (const float*)d_in[4];  prm.r2 = (const float*)d_in[5];  prm.b2 = (const float*)d_in[6];
  prm.k3 = (const float*)d_in[7];  prm.r3 = (const float*)d_in[8];  prm.b3 = (const float*)d_in[9];
  prm.k4 = (const float*)d_in[10]; prm.r4 = (const float*)d_in[11]; prm.b4 = (const float*)d_in[12];
  prm.wd1 = (const float*)d_in[13]; prm.bd1 = (const float*)d_in[14];
  prm.wd2 = (const float*)d_in[15]; prm.bd2 = (const float*)d_in[16];
  prm.wd3 = (const float*)d_in[17]; prm.bd3 = (const float*)d_in[18];
  prm.wd4 = (const float*)d_in[19]; prm.bd4 = (const float*)d_in[20];
  prm.wd5 = (const float*)d_in[21]; prm.bd5 = (const float*)d_in[22];
  prm.wd6 = (const float*)d_in[23]; prm.bd6 = (const float*)d_in[24];
  prm.out = (float*)d_out;
  prm.ws  = (char*)d_ws;

  const bool big = ws_size >= WS<TSTEPS>::END;
  const size_t bar_off = big ? WS<TSTEPS>::BAR : WS<4>::BAR;
  // zero the sync area AND the h[-1] zero-region (contiguous)
  hipMemsetAsync((char*)d_ws + bar_off, 0, 8192 + 163840, stream);

  void* args[] = { &prm };
  if (big) {
    hipLaunchCooperativeKernel((void*)fused_kernel<TSTEPS>, dim3(NGRID), dim3(NT),
                               args, 0, stream);
  } else {
    hipLaunchCooperativeKernel((void*)fused_kernel<4>, dim3(NGRID), dim3(NT),
                               args, 0, stream);
  }
}